// Round 2
// baseline (113.685 us; speedup 1.0000x reference)
//
#include <hip/hip_runtime.h>
#include <hip/hip_bf16.h>

// GATConv reduces algebraically to a permuted-column GEMM:
//   out[n, c] = sum_k x[n,k] * W[(c%8)*64 + c/8, k] + bias[c]
// (the reference einsum contracts alpha over its softmax axis -> sum == 1).
// N=4096, K=256, M=512.
//
// R2 restructure: the op is tiny (1.07 GFLOP, 12.5 MB compulsory HBM), so the
// old single-kernel version (512 blocks = 2 waves/SIMD, stage->barrier->MFMA
// serial chain per block) was latency-bound, not throughput-bound.
// New shape:
//   k1: convert x->bf16 and W->bf16 WITH the column permutation pre-applied,
//       into d_ws (~6.75 MB traffic, ~2 us).
//   k2: LDS-free, barrier-free GEMM: each wave owns a 16x16 output tile and
//       reads its MFMA fragments straight from bf16 global (L2/L3-resident).
//       8 loadx4 (A) + 8 loadx4 (B) + 8 MFMA + 4 stores per lane, ~45 VGPR,
//       2048 blocks x 256 thr = 32 waves/CU for latency hiding.

typedef __attribute__((ext_vector_type(8))) short bf16x8;   // 8 bf16 (4 VGPRs)
typedef __attribute__((ext_vector_type(4))) float floatx4;  // MFMA accumulator

__device__ __forceinline__ short f2bf(float f) {
    union { __hip_bfloat16 h; short s; } u;
    u.h = __float2bfloat16(f);   // RNE
    return u.s;
}

// ---- k1: fp32 -> bf16 convert; W gets the output-column permutation ----
// x: 4096*256 = 262144 float4; W: 512*256 = 32768 float4.
__global__ __launch_bounds__(256) void convert_bf16(
    const float* __restrict__ x,   // [4096,256]
    const float* __restrict__ W,   // [512,256]
    short* __restrict__ xb,        // [4096,256] bf16
    short* __restrict__ wb)        // [512,256] bf16, wb[c][k] = W[perm(c)][k]
{
    const int i = blockIdx.x * 256 + threadIdx.x;   // float4 index, 0..262143

    float4 v = ((const float4*)x)[i];
    short4 s;
    s.x = f2bf(v.x); s.y = f2bf(v.y); s.z = f2bf(v.z); s.w = f2bf(v.w);
    ((short4*)xb)[i] = s;

    if (i < 32768) {
        int c  = i >> 6;            // output column 0..511
        int c4 = i & 63;            // float4 within row
        int wrow = ((c & 7) << 6) + (c >> 3);   // perm(c)
        float4 wv = ((const float4*)W)[wrow * 64 + c4];
        short4 ws;
        ws.x = f2bf(wv.x); ws.y = f2bf(wv.y); ws.z = f2bf(wv.z); ws.w = f2bf(wv.w);
        ((short4*)wb)[i] = ws;
    }
}

// ---- k2: barrier-free bf16 GEMM, one 16x16 tile per wave ----
// Block = 4 waves arranged 2x2 -> 32x32 output per block (L1 locality).
// Grid (512/32, 4096/32) = (16,128) = 2048 blocks, 8 blocks/CU, 32 waves/CU.
__global__ __launch_bounds__(256) void gat_gemm(
    const short* __restrict__ xb,   // [4096,256] bf16
    const short* __restrict__ wb,   // [512,256] bf16 (pre-permuted)
    const float* __restrict__ bias, // [512]
    float* __restrict__ out)        // [4096,512]
{
    const int tid  = threadIdx.x;
    const int wv   = tid >> 6;          // 0..3
    const int lane = tid & 63;
    const int mrow = lane & 15;         // A row / B col within tile
    const int quad = lane >> 4;         // k-subblock (input), row-subblock (output)

    const int rowBase = blockIdx.y * 32 + (wv >> 1) * 16;
    const int colBase = blockIdx.x * 32 + (wv & 1) * 16;

    // fragment pointers: A row = rowBase+mrow, B row = colBase+mrow (pre-permuted),
    // k offset = kb*32 + quad*8  (identical fragment layout to the verified
    // LDS version, just sourced from global).
    const short* ap = &xb[(rowBase + mrow) * 256 + quad * 8];
    const short* bp = &wb[(colBase + mrow) * 256 + quad * 8];

    floatx4 acc = {0.f, 0.f, 0.f, 0.f};
    #pragma unroll
    for (int kb = 0; kb < 8; ++kb) {
        bf16x8 af = *(const bf16x8*)(ap + kb * 32);
        bf16x8 bf = *(const bf16x8*)(bp + kb * 32);
        acc = __builtin_amdgcn_mfma_f32_16x16x32_bf16(af, bf, acc, 0, 0, 0);
    }

    // C/D layout: col = lane&15, row = quad*4 + r
    const int col = colBase + mrow;
    const float bv = bias[col];
    #pragma unroll
    for (int r = 0; r < 4; ++r) {
        int row = rowBase + quad * 4 + r;
        out[row * 512 + col] = acc[r] + bv;
    }
}

extern "C" void kernel_launch(void* const* d_in, const int* in_sizes, int n_in,
                              void* d_out, int out_size, void* d_ws, size_t ws_size,
                              hipStream_t stream) {
    // setup_inputs order: 0=adj (unused), 1=x, 2=W, 3=att_src (unused),
    //                     4=att_dst (unused), 5=bias
    const float* x    = (const float*)d_in[1];
    const float* W    = (const float*)d_in[2];
    const float* bias = (const float*)d_in[5];
    float* out        = (float*)d_out;

    short* xb = (short*)d_ws;                                  // 4096*256*2 = 2 MiB
    short* wb = (short*)((char*)d_ws + 4096 * 256 * 2);        // 512*256*2 = 256 KiB

    hipLaunchKernelGGL(convert_bf16, dim3(1024), dim3(256), 0, stream, x, W, xb, wb);
    hipLaunchKernelGGL(gat_gemm, dim3(16, 128), dim3(256), 0, stream, xb, wb, bias, out);
}